// Round 4
// baseline (169.542 us; speedup 1.0000x reference)
//
#include <hip/hip_runtime.h>
#include <hip/hip_bf16.h>

typedef unsigned short u16;
typedef unsigned int u32;
typedef float f32x4 __attribute__((ext_vector_type(4)));
typedef int i32x4 __attribute__((ext_vector_type(4)));
typedef int i32x8 __attribute__((ext_vector_type(8)));

#define N_ROWS 8192
#define DIM 512
#define BM 128
#define BN 128
#define NREP 8             // accumulator replicas
// sqrt(log2(e)/0.07): folded into stored fp8 so MFMA emits sim/T*log2(e)
// directly and the epilogue uses raw v_exp_f32 (exp2) with no extra mul.
#define SCALE 4.5398160f
// E8M0 unit scale (127 -> 2^0) replicated in all 4 bytes
#define SCALE1 0x7F7F7F7F

// ------- kernel 1: L2-normalize rows -> fp8 e4m3 (pre-scaled); zero accs ---
__global__ __launch_bounds__(256) void norm_cast_kernel(
        const float* __restrict__ x, u32* __restrict__ hb8,
        float* __restrict__ accR /* 2*NREP*N_ROWS floats */,
        float* __restrict__ out) {
    int gid = blockIdx.x * 256 + threadIdx.x;
    if (gid < 2 * NREP * N_ROWS) accR[gid] = 0.f;
    if (gid == 0) out[0] = 0.f;
    int row  = blockIdx.x * 4 + (threadIdx.x >> 6);
    int lane = threadIdx.x & 63;
    const float4* xr = (const float4*)(x + (size_t)row * DIM);
    float4 v0 = xr[lane * 2 + 0];
    float4 v1 = xr[lane * 2 + 1];
    float ss = v0.x * v0.x + v0.y * v0.y + v0.z * v0.z + v0.w * v0.w
             + v1.x * v1.x + v1.y * v1.y + v1.z * v1.z + v1.w * v1.w;
#pragma unroll
    for (int off = 32; off; off >>= 1) ss += __shfl_xor(ss, off);
    float s = SCALE / fmaxf(sqrtf(ss), 1e-12f);
    // pack 8 fp8 (OCP e4m3 on gfx950, RNE+sat in HW)
    int w0 = __builtin_amdgcn_cvt_pk_fp8_f32(v0.x * s, v0.y * s, 0, false);
    w0     = __builtin_amdgcn_cvt_pk_fp8_f32(v0.z * s, v0.w * s, w0, true);
    int w1 = __builtin_amdgcn_cvt_pk_fp8_f32(v1.x * s, v1.y * s, 0, false);
    w1     = __builtin_amdgcn_cvt_pk_fp8_f32(v1.z * s, v1.w * s, w1, true);
    uint2 o; o.x = (u32)w0; o.y = (u32)w1;
    ((uint2*)((char*)hb8 + (size_t)row * DIM + lane * 8))[0] = o;
}

// stage helper: immediate offset must be a constant-expression for
// __builtin_amdgcn_global_load_lds -> template parameter (R9 compile fix).
template <int K0OFF>
__device__ __forceinline__ void stage_tiles(
        const char* const* gA, const char* const* gB,
        char* ldsA, char* ldsB, int tid) {
#pragma unroll
    for (int s2 = 0; s2 < 4; ++s2) {
        int seg = tid + s2 * 256;
        __builtin_amdgcn_global_load_lds(
            (const __attribute__((address_space(1))) void*)gA[s2],
            (__attribute__((address_space(3))) void*)&ldsA[seg * 16],
            16, K0OFF, 0);
        __builtin_amdgcn_global_load_lds(
            (const __attribute__((address_space(1))) void*)gB[s2],
            (__attribute__((address_space(3))) void*)&ldsB[seg * 16],
            16, K0OFF, 0);
    }
}

// ------- kernel 2: triangular fused tile GEMM (MX fp8) + exp2 + sums -------
// R8 pair schedule unchanged (FETCH 13 MB, balance 8-9 tiles/CU — proven).
// GEMM core: mfma_scale_f32_16x16x128_f8f6f4 with unit E8M0 scales (x1.0):
// 2x instruction rate vs plain fp8 (m148 ladder), K=128 per MFMA -> each
// lane's fragment is 32 contiguous bytes: two ds_read_b128 at {addr, addr^16}
// (XOR swizzle maps the chunk pair to slot pair {s, s^1}), kk loop gone.
__global__ __launch_bounds__(256) void tile_kernel(
        const char* __restrict__ hb8, const int* __restrict__ labels,
        float* __restrict__ rowTotalR, float* __restrict__ rowPosR) {
    __shared__ __align__(16) char ldsA[BM * 128];   // 16 KB
    __shared__ __align__(16) char ldsB[BN * 128];   // 16 KB
    __shared__ int labR[BM];
    __shared__ int labC[BN];
    __shared__ float cT[2][BN], cP[2][BN];
    __shared__ float rT[2][BM], rP[2][BM];

    const int b = blockIdx.x;
    const int c = b & 255;          // CU slot (round-robin)
    const int m = b >> 8;           // step 0..8
    const int y = c >> 3;
    const int p = 4 * (c & 7) + (y & 3);    // pair id [0,32)
    const int j = y >> 2;                   // CU within pair [0,8)
    const int t = j + 8 * m;                // tile index within pair
    if (t >= 65) return;
    int ti, tj;
    if (t <= p) { tj = p; ti = t; }
    else        { tj = 63 - p; ti = t - p - 1; }

    const int rowBase = ti * BM;
    const int colBase = tj * BN;
    const bool isDiag = (ti == tj);
    const int dd = colBase - rowBase;
    const int rep = (ti + tj) & (NREP - 1);
    const int tid = threadIdx.x;

    if (tid < 128) labR[tid] = labels[rowBase + tid];
    else           labC[tid - 128] = labels[colBase + tid - 128];

    const int w = tid >> 6;
    const int lane = tid & 63;
    const int wm = (w >> 1) * 64;
    const int wn = (w & 1) * 64;
    const int wr = w >> 1;
    const int wc = w & 1;
    const int quad = lane >> 4;     // = K-group of the fragment (l>>4)
    const int l16 = lane & 15;

    // staging bases (computed once; k0 advances via immediate offset)
    const char* gA[4]; const char* gB[4];
#pragma unroll
    for (int s2 = 0; s2 < 4; ++s2) {
        int seg = tid + s2 * 256;         // 0..1023
        int r = seg >> 3;                 // 0..127
        int sl = seg & 7;                 // LDS 16-B slot
        int g = sl ^ (r & 7);             // global 16-B chunk within 128-B row-slice
        gA[s2] = hb8 + (size_t)(rowBase + r) * DIM + g * 16;
        gB[s2] = hb8 + (size_t)(colBase + r) * DIM + g * 16;
    }

    f32x4 acc[4][4];
#pragma unroll
    for (int i = 0; i < 4; ++i)
#pragma unroll
        for (int jj = 0; jj < 4; ++jj)
            acc[i][jj] = (f32x4){0.f, 0.f, 0.f, 0.f};

#pragma unroll
    for (int k0 = 0; k0 < 4; ++k0) {      // BK=128 bytes, imm offset k0*128
        switch (k0) {
            case 0: stage_tiles<0>(gA, gB, ldsA, ldsB, tid); break;
            case 1: stage_tiles<128>(gA, gB, ldsA, ldsB, tid); break;
            case 2: stage_tiles<256>(gA, gB, ldsA, ldsB, tid); break;
            default: stage_tiles<384>(gA, gB, ldsA, ldsB, tid); break;
        }
        __syncthreads();                  // drain + barrier
        // lane's 32 K-bytes = global chunks {2*quad, 2*quad+1} of its row.
        // chunk g sits at LDS slot g^(r&7); the pair lands at slots {s,s^1}
        // -> second read is addr^16, K-order restored by explicit lo/hi.
        i32x8 bf[4];
#pragma unroll
        for (int in = 0; in < 4; ++in) {
            int col = wn + in * 16 + l16;
            int base = col * 128 + (((2 * quad) ^ (col & 7)) * 16);
            i32x4 lo = *(const i32x4*)&ldsB[base];
            i32x4 hi = *(const i32x4*)&ldsB[base ^ 16];
#pragma unroll
            for (int q2 = 0; q2 < 4; ++q2) { bf[in][q2] = lo[q2]; bf[in][q2 + 4] = hi[q2]; }
        }
#pragma unroll
        for (int im = 0; im < 4; ++im) {
            int row = wm + im * 16 + l16;
            int base = row * 128 + (((2 * quad) ^ (row & 7)) * 16);
            i32x4 lo = *(const i32x4*)&ldsA[base];
            i32x4 hi = *(const i32x4*)&ldsA[base ^ 16];
            i32x8 af;
#pragma unroll
            for (int q2 = 0; q2 < 4; ++q2) { af[q2] = lo[q2]; af[q2 + 4] = hi[q2]; }
#pragma unroll
            for (int in = 0; in < 4; ++in)
                acc[im][in] = __builtin_amdgcn_mfma_scale_f32_16x16x128_f8f6f4(
                    af, bf[in], acc[im][in], 0 /*cbsz: fp8*/, 0 /*blgp: fp8*/,
                    0, SCALE1, 0, SCALE1);
        }
        __syncthreads();                  // protect buffers before next stage
    }

    // ---------------- epilogue (acc already = sim/T * log2e) ----------------
    int lc[4];
#pragma unroll
    for (int in = 0; in < 4; ++in) lc[in] = labC[wn + in * 16 + l16];

    float colT[4] = {0.f, 0.f, 0.f, 0.f}, colP[4] = {0.f, 0.f, 0.f, 0.f};
#pragma unroll
    for (int im = 0; im < 4; ++im) {
        float rowT[4] = {0.f, 0.f, 0.f, 0.f}, rowP[4] = {0.f, 0.f, 0.f, 0.f};
#pragma unroll
        for (int reg = 0; reg < 4; ++reg) {
            int rloc = wm + im * 16 + quad * 4 + reg;
            int li = labR[rloc];
#pragma unroll
            for (int in = 0; in < 4; ++in) {
                int cloc = wn + in * 16 + l16;
                float e = __builtin_exp2f(acc[im][in][reg]);  // v_exp_f32, no mul
                bool pos = (lc[in] == li) && (rloc - cloc != dd);
                colT[in] += e; rowT[reg] += e;
                if (pos) { colP[in] += e; rowP[reg] += e; }
            }
        }
        if (!isDiag) {
#pragma unroll
            for (int reg = 0; reg < 4; ++reg) {
                float tt = rowT[reg], pp = rowP[reg];
                tt += __shfl_xor(tt, 1); tt += __shfl_xor(tt, 2);
                tt += __shfl_xor(tt, 4); tt += __shfl_xor(tt, 8);
                pp += __shfl_xor(pp, 1); pp += __shfl_xor(pp, 2);
                pp += __shfl_xor(pp, 4); pp += __shfl_xor(pp, 8);
                if (l16 == 0) {
                    int rloc = wm + im * 16 + quad * 4 + reg;
                    rT[wc][rloc] = tt;
                    rP[wc][rloc] = pp;
                }
            }
        }
    }
#pragma unroll
    for (int in = 0; in < 4; ++in) {
        float tt = colT[in], pp = colP[in];
        tt += __shfl_xor(tt, 16); tt += __shfl_xor(tt, 32);
        pp += __shfl_xor(pp, 16); pp += __shfl_xor(pp, 32);
        if (quad == 0) {
            int cloc = wn + in * 16 + l16;
            cT[wr][cloc] = tt;
            cP[wr][cloc] = pp;
        }
    }
    __syncthreads();
    float* rowTotal = rowTotalR + rep * N_ROWS;
    float* rowPos   = rowPosR   + rep * N_ROWS;
    if (tid < 128) {
        atomicAdd(&rowTotal[colBase + tid], cT[0][tid] + cT[1][tid]);
        if (!isDiag) atomicAdd(&rowTotal[rowBase + tid], rT[0][tid] + rT[1][tid]);
    } else {
        int t2 = tid - 128;
        atomicAdd(&rowPos[colBase + t2], cP[0][t2] + cP[1][t2]);
        if (!isDiag) atomicAdd(&rowPos[rowBase + t2], rP[0][t2] + rP[1][t2]);
    }
}

// ------- kernel 3: fold replicas + histogram + loss (64 blocks) ------------
__global__ __launch_bounds__(256) void reduce_loss_kernel(
        const int* __restrict__ labels, const float* __restrict__ rowTotalR,
        const float* __restrict__ rowPosR, float* __restrict__ out) {
    __shared__ int hist[128];
    __shared__ float red[256];
    int tid = threadIdx.x;
    if (tid < 128) hist[tid] = 0;
    __syncthreads();
    for (int i = tid; i < N_ROWS; i += 256)
        atomicAdd(&hist[labels[i] & 127], 1);
    __syncthreads();
    float sacc = 0.f;
    if (tid < 128) {
        int row = blockIdx.x * 128 + tid;
        float T = 0.f, P = 0.f;
#pragma unroll
        for (int r = 0; r < NREP; ++r) {
            T += rowTotalR[r * N_ROWS + row];
            P += rowPosR[r * N_ROWS + row];
        }
        float cc = (float)(hist[labels[row] & 127] - 1);
        sacc = logf((P / (cc + 1e-9f)) / T);
    }
    red[tid] = sacc;
    __syncthreads();
    for (int st = 128; st; st >>= 1) {
        if (tid < st) red[tid] += red[tid + st];
        __syncthreads();
    }
    if (tid == 0) atomicAdd(out, -red[0] / (float)N_ROWS);
}

extern "C" void kernel_launch(void* const* d_in, const int* in_sizes, int n_in,
                              void* d_out, int out_size, void* d_ws, size_t ws_size,
                              hipStream_t stream) {
    const float* hidden = (const float*)d_in[0];
    const int* labels   = (const int*)d_in[1];
    float* out = (float*)d_out;

    char* ws = (char*)d_ws;
    char* hb8 = ws;                                          // 8192*512 = 4 MB
    float* rowTotalR = (float*)(ws + (size_t)N_ROWS * DIM);  // NREP*8192 f
    float* rowPosR   = rowTotalR + NREP * N_ROWS;            // NREP*8192 f

    norm_cast_kernel<<<N_ROWS / 4, 256, 0, stream>>>(hidden, (u32*)hb8, rowTotalR, out);
    tile_kernel<<<9 * 256, 256, 0, stream>>>(hb8, labels, rowTotalR, rowPosR);
    reduce_loss_kernel<<<64, 256, 0, stream>>>(labels, rowTotalR, rowPosR, out);
}

// Round 6
// 161.224 us; speedup vs baseline: 1.0516x; 1.0516x over previous
//
#include <hip/hip_runtime.h>
#include <hip/hip_bf16.h>

typedef unsigned short u16;
typedef unsigned int u32;
typedef float f32x4 __attribute__((ext_vector_type(4)));

#define N_ROWS 8192
#define DIM 512
#define BM 128
#define BN 128
#define NREP 8             // accumulator replicas
#define NBLOCKS 2304       // tile_kernel grid (9*256); ALL increment the counter
// sqrt(log2(e)/0.07): folded into stored fp8 so MFMA emits sim/T*log2(e)
// directly and the epilogue uses raw v_exp_f32 (exp2) with no extra mul.
#define SCALE 4.5398160f

// ------- kernel 1: L2-normalize rows -> fp8 e4m3 (pre-scaled); zero accs ---
__global__ __launch_bounds__(256) void norm_cast_kernel(
        const float* __restrict__ x, u32* __restrict__ hb8,
        float* __restrict__ accR /* 2*NREP*N_ROWS floats */,
        float* __restrict__ out, u32* __restrict__ cnt) {
    int gid = blockIdx.x * 256 + threadIdx.x;
    if (gid < 2 * NREP * N_ROWS) accR[gid] = 0.f;
    if (gid == 0) { out[0] = 0.f; cnt[0] = 0u; }
    int row  = blockIdx.x * 4 + (threadIdx.x >> 6);
    int lane = threadIdx.x & 63;
    const float4* xr = (const float4*)(x + (size_t)row * DIM);
    float4 v0 = xr[lane * 2 + 0];
    float4 v1 = xr[lane * 2 + 1];
    float ss = v0.x * v0.x + v0.y * v0.y + v0.z * v0.z + v0.w * v0.w
             + v1.x * v1.x + v1.y * v1.y + v1.z * v1.z + v1.w * v1.w;
#pragma unroll
    for (int off = 32; off; off >>= 1) ss += __shfl_xor(ss, off);
    float s = SCALE / fmaxf(sqrtf(ss), 1e-12f);
    // pack 8 fp8 (OCP e4m3 on gfx950, RNE+sat in HW)
    int w0 = __builtin_amdgcn_cvt_pk_fp8_f32(v0.x * s, v0.y * s, 0, false);
    w0     = __builtin_amdgcn_cvt_pk_fp8_f32(v0.z * s, v0.w * s, w0, true);
    int w1 = __builtin_amdgcn_cvt_pk_fp8_f32(v1.x * s, v1.y * s, 0, false);
    w1     = __builtin_amdgcn_cvt_pk_fp8_f32(v1.z * s, v1.w * s, w1, true);
    uint2 o; o.x = (u32)w0; o.y = (u32)w1;
    ((uint2*)((char*)hb8 + (size_t)row * DIM + lane * 8))[0] = o;
}

// stage helper: immediate offset must be a constant-expression for
// __builtin_amdgcn_global_load_lds -> template parameter.
template <int K0OFF>
__device__ __forceinline__ void stage_tiles(
        const char* const* gA, const char* const* gB,
        char* ldsA, char* ldsB, int tid) {
#pragma unroll
    for (int s2 = 0; s2 < 4; ++s2) {
        int seg = tid + s2 * 256;
        __builtin_amdgcn_global_load_lds(
            (const __attribute__((address_space(1))) void*)gA[s2],
            (__attribute__((address_space(3))) void*)&ldsA[seg * 16],
            16, K0OFF, 0);
        __builtin_amdgcn_global_load_lds(
            (const __attribute__((address_space(1))) void*)gB[s2],
            (__attribute__((address_space(3))) void*)&ldsB[seg * 16],
            16, K0OFF, 0);
    }
}

__device__ __forceinline__ float agent_load(const float* p) {
    // coherent-point load: other XCDs' atomicAdd results, bypassing stale L1/L2
    return __hip_atomic_load(p, __ATOMIC_RELAXED, __HIP_MEMORY_SCOPE_AGENT);
}

// fused final reduction: histogram + per-row loss + block reduce (one block)
__device__ __forceinline__ void final_reduce(
        const int* __restrict__ labels, const float* __restrict__ rowTotalR,
        const float* __restrict__ rowPosR, float* __restrict__ out,
        int* hist, float* red, int tid) {
    if (tid < 128) hist[tid] = 0;
    __syncthreads();
    for (int i = tid; i < N_ROWS; i += 256)
        atomicAdd(&hist[labels[i] & 127], 1);
    __syncthreads();
    float sacc = 0.f;
    for (int row = tid; row < N_ROWS; row += 256) {
        float T = 0.f, P = 0.f;
#pragma unroll
        for (int r = 0; r < NREP; ++r) {
            T += agent_load(&rowTotalR[r * N_ROWS + row]);
            P += agent_load(&rowPosR[r * N_ROWS + row]);
        }
        float cc = (float)(hist[labels[row] & 127] - 1);
        sacc += logf((P / (cc + 1e-9f)) / T);
    }
    red[tid] = sacc;
    __syncthreads();
    for (int st = 128; st; st >>= 1) {
        if (tid < st) red[tid] += red[tid + st];
        __syncthreads();
    }
    if (tid == 0) out[0] = -red[0] / (float)N_ROWS;   // sole writer
}

// ------- kernel 2: triangular fused tile GEMM (fp8) + exp2 + sums ----------
// R2-PROVEN core (54.7us, passed): stage -> sync -> compute -> sync per BK=128.
// R4's pipelined dbuf NaN'd (m152-style race) -> reverted, not retried.
// NEW: last-block-done fused loss reduction (deletes the 3rd kernel launch).
__global__ __launch_bounds__(256) void tile_kernel(
        const char* __restrict__ hb8, const int* __restrict__ labels,
        float* __restrict__ rowTotalR, float* __restrict__ rowPosR,
        u32* __restrict__ cnt, float* __restrict__ out) {
    __shared__ __align__(16) char ldsA[BM * 128];   // 16 KB
    __shared__ __align__(16) char ldsB[BN * 128];   // 16 KB
    __shared__ int labR[BM];
    __shared__ int labC[BN];
    __shared__ float cT[2][BN], cP[2][BN];
    __shared__ float rT[2][BM], rP[2][BM];
    __shared__ int hist[128];
    __shared__ float red[256];
    __shared__ int lastFlag;

    const int b = blockIdx.x;
    const int c = b & 255;          // CU slot (round-robin)
    const int m = b >> 8;           // step 0..8
    const int y = c >> 3;
    const int p = 4 * (c & 7) + (y & 3);    // pair id [0,32)
    const int j = y >> 2;                   // CU within pair [0,8)
    const int t = j + 8 * m;                // tile index within pair
    const int tid = threadIdx.x;
    if (t >= 65) {
        // dead block: still counts toward the done-counter. It can only win
        // as the 2304th incrementer, i.e. after every worker's contributions.
        if (tid == 0) lastFlag = ((int)atomicAdd(cnt, 1u) == NBLOCKS - 1);
        __syncthreads();
        if (lastFlag) final_reduce(labels, rowTotalR, rowPosR, out, hist, red, tid);
        return;
    }
    int ti, tj;
    if (t <= p) { tj = p; ti = t; }
    else        { tj = 63 - p; ti = t - p - 1; }

    const int rowBase = ti * BM;
    const int colBase = tj * BN;
    const bool isDiag = (ti == tj);
    const int dd = colBase - rowBase;
    const int rep = (ti + tj) & (NREP - 1);

    if (tid < 128) labR[tid] = labels[rowBase + tid];
    else           labC[tid - 128] = labels[colBase + tid - 128];

    const int w = tid >> 6;
    const int lane = tid & 63;
    const int wm = (w >> 1) * 64;
    const int wn = (w & 1) * 64;
    const int wr = w >> 1;
    const int wc = w & 1;
    const int quad = lane >> 4;
    const int l16 = lane & 15;

    // staging bases (computed once; k0 advances via immediate offset)
    const char* gA[4]; const char* gB[4];
#pragma unroll
    for (int s2 = 0; s2 < 4; ++s2) {
        int seg = tid + s2 * 256;         // 0..1023
        int r = seg >> 3;                 // 0..127
        int sl = seg & 7;                 // LDS 16-B slot
        int g = sl ^ (r & 7);             // global 16-B chunk within 128-B row-slice
        gA[s2] = hb8 + (size_t)(rowBase + r) * DIM + g * 16;
        gB[s2] = hb8 + (size_t)(colBase + r) * DIM + g * 16;
    }

    f32x4 acc[4][4];
#pragma unroll
    for (int i = 0; i < 4; ++i)
#pragma unroll
        for (int jj = 0; jj < 4; ++jj)
            acc[i][jj] = (f32x4){0.f, 0.f, 0.f, 0.f};

#pragma unroll
    for (int k0 = 0; k0 < 4; ++k0) {      // BK=128 bytes, imm offset k0*128
        switch (k0) {
            case 0: stage_tiles<0>(gA, gB, ldsA, ldsB, tid); break;
            case 1: stage_tiles<128>(gA, gB, ldsA, ldsB, tid); break;
            case 2: stage_tiles<256>(gA, gB, ldsA, ldsB, tid); break;
            default: stage_tiles<384>(gA, gB, ldsA, ldsB, tid); break;
        }
        __syncthreads();                  // drain + barrier
#pragma unroll
        for (int kk = 0; kk < 4; ++kk) {  // four K=32 MFMA steps per BK=128
            long af[4], bfr[4];
#pragma unroll
            for (int im = 0; im < 4; ++im) {
                int row = wm + im * 16 + l16;
                int c4 = kk * 2 + (quad >> 1);
                int sl = c4 ^ (row & 7);
                af[im] = *(const long*)&ldsA[row * 128 + sl * 16 + (quad & 1) * 8];
            }
#pragma unroll
            for (int in = 0; in < 4; ++in) {
                int col = wn + in * 16 + l16;
                int c4 = kk * 2 + (quad >> 1);
                int sl = c4 ^ (col & 7);
                bfr[in] = *(const long*)&ldsB[col * 128 + sl * 16 + (quad & 1) * 8];
            }
#pragma unroll
            for (int im = 0; im < 4; ++im)
#pragma unroll
                for (int in = 0; in < 4; ++in)
                    acc[im][in] = __builtin_amdgcn_mfma_f32_16x16x32_fp8_fp8(
                        af[im], bfr[in], acc[im][in], 0, 0, 0);
        }
        __syncthreads();                  // protect buffers before next stage
    }

    // ---------------- epilogue (acc already = sim/T * log2e) ----------------
    int lc[4];
#pragma unroll
    for (int in = 0; in < 4; ++in) lc[in] = labC[wn + in * 16 + l16];

    float colT[4] = {0.f, 0.f, 0.f, 0.f}, colP[4] = {0.f, 0.f, 0.f, 0.f};
#pragma unroll
    for (int im = 0; im < 4; ++im) {
        float rowT[4] = {0.f, 0.f, 0.f, 0.f}, rowP[4] = {0.f, 0.f, 0.f, 0.f};
#pragma unroll
        for (int reg = 0; reg < 4; ++reg) {
            int rloc = wm + im * 16 + quad * 4 + reg;
            int li = labR[rloc];
#pragma unroll
            for (int in = 0; in < 4; ++in) {
                int cloc = wn + in * 16 + l16;
                float e = __builtin_exp2f(acc[im][in][reg]);  // v_exp_f32, no mul
                bool pos = (lc[in] == li) && (rloc - cloc != dd);
                colT[in] += e; rowT[reg] += e;
                if (pos) { colP[in] += e; rowP[reg] += e; }
            }
        }
        if (!isDiag) {
#pragma unroll
            for (int reg = 0; reg < 4; ++reg) {
                float tt = rowT[reg], pp = rowP[reg];
                tt += __shfl_xor(tt, 1); tt += __shfl_xor(tt, 2);
                tt += __shfl_xor(tt, 4); tt += __shfl_xor(tt, 8);
                pp += __shfl_xor(pp, 1); pp += __shfl_xor(pp, 2);
                pp += __shfl_xor(pp, 4); pp += __shfl_xor(pp, 8);
                if (l16 == 0) {
                    int rloc = wm + im * 16 + quad * 4 + reg;
                    rT[wc][rloc] = tt;
                    rP[wc][rloc] = pp;
                }
            }
        }
    }
#pragma unroll
    for (int in = 0; in < 4; ++in) {
        float tt = colT[in], pp = colP[in];
        tt += __shfl_xor(tt, 16); tt += __shfl_xor(tt, 32);
        pp += __shfl_xor(pp, 16); pp += __shfl_xor(pp, 32);
        if (quad == 0) {
            int cloc = wn + in * 16 + l16;
            cT[wr][cloc] = tt;
            cP[wr][cloc] = pp;
        }
    }
    __syncthreads();
    float* rowTotal = rowTotalR + rep * N_ROWS;
    float* rowPos   = rowPosR   + rep * N_ROWS;
    if (tid < 128) {
        atomicAdd(&rowTotal[colBase + tid], cT[0][tid] + cT[1][tid]);
        if (!isDiag) atomicAdd(&rowTotal[rowBase + tid], rT[0][tid] + rT[1][tid]);
    } else {
        int t2 = tid - 128;
        atomicAdd(&rowPos[colBase + t2], cP[0][t2] + cP[1][t2]);
        if (!isDiag) atomicAdd(&rowPos[rowBase + t2], rP[0][t2] + rP[1][t2]);
    }

    // ---- last-block-done: the 2304th incrementer runs the loss reduction ----
    __syncthreads();   // all waves' atomics drained (vmcnt(0) before barrier)
    if (tid == 0) {
        __threadfence();
        lastFlag = ((int)atomicAdd(cnt, 1u) == NBLOCKS - 1);
    }
    __syncthreads();
    if (lastFlag) final_reduce(labels, rowTotalR, rowPosR, out, hist, red, tid);
}

extern "C" void kernel_launch(void* const* d_in, const int* in_sizes, int n_in,
                              void* d_out, int out_size, void* d_ws, size_t ws_size,
                              hipStream_t stream) {
    const float* hidden = (const float*)d_in[0];
    const int* labels   = (const int*)d_in[1];
    float* out = (float*)d_out;

    char* ws = (char*)d_ws;
    char* hb8 = ws;                                          // 8192*512 = 4 MB
    float* rowTotalR = (float*)(ws + (size_t)N_ROWS * DIM);  // NREP*8192 f
    float* rowPosR   = rowTotalR + NREP * N_ROWS;            // NREP*8192 f
    u32* cnt         = (u32*)(rowPosR + NREP * N_ROWS);      // 1 u32

    norm_cast_kernel<<<N_ROWS / 4, 256, 0, stream>>>(hidden, (u32*)hb8, rowTotalR, out, cnt);
    tile_kernel<<<NBLOCKS, 256, 0, stream>>>(hb8, labels, rowTotalR, rowPosR, cnt, out);
}

// Round 7
// 158.604 us; speedup vs baseline: 1.0690x; 1.0165x over previous
//
#include <hip/hip_runtime.h>
#include <hip/hip_bf16.h>

typedef unsigned short u16;
typedef unsigned int u32;
typedef float f32x4 __attribute__((ext_vector_type(4)));

#define N_ROWS 8192
#define DIM 512
#define BM 128
#define BN 128
#define NREP 8             // accumulator replicas
#define NTILES 2080        // 65*32 triangular tiles (with diagonal)
#define GRID_P 1024        // persistent blocks = 4/CU * 256 CU (LDS capacity)
#define FINB 64            // last-64 blocks fold the loss in parallel
// sqrt(log2(e)/0.07): folded into stored fp8 so MFMA emits sim/T*log2(e)
// directly and the epilogue uses raw v_exp_f32 (exp2) with no extra mul.
#define SCALE 4.5398160f

// ------- kernel 1: L2-normalize rows -> fp8 e4m3 (pre-scaled); zero accs ---
__global__ __launch_bounds__(256) void norm_cast_kernel(
        const float* __restrict__ x, u32* __restrict__ hb8,
        float* __restrict__ accR /* 2*NREP*N_ROWS floats */,
        float* __restrict__ out, u32* __restrict__ cnt) {
    int gid = blockIdx.x * 256 + threadIdx.x;
    if (gid < 2 * NREP * N_ROWS) accR[gid] = 0.f;
    if (gid == 0) { out[0] = 0.f; cnt[0] = 0u; cnt[1] = 0u; }
    int row  = blockIdx.x * 4 + (threadIdx.x >> 6);
    int lane = threadIdx.x & 63;
    const float4* xr = (const float4*)(x + (size_t)row * DIM);
    float4 v0 = xr[lane * 2 + 0];
    float4 v1 = xr[lane * 2 + 1];
    float ss = v0.x * v0.x + v0.y * v0.y + v0.z * v0.z + v0.w * v0.w
             + v1.x * v1.x + v1.y * v1.y + v1.z * v1.z + v1.w * v1.w;
#pragma unroll
    for (int off = 32; off; off >>= 1) ss += __shfl_xor(ss, off);
    float s = SCALE / fmaxf(sqrtf(ss), 1e-12f);
    // pack 8 fp8 (OCP e4m3 on gfx950, RNE+sat in HW)
    int w0 = __builtin_amdgcn_cvt_pk_fp8_f32(v0.x * s, v0.y * s, 0, false);
    w0     = __builtin_amdgcn_cvt_pk_fp8_f32(v0.z * s, v0.w * s, w0, true);
    int w1 = __builtin_amdgcn_cvt_pk_fp8_f32(v1.x * s, v1.y * s, 0, false);
    w1     = __builtin_amdgcn_cvt_pk_fp8_f32(v1.z * s, v1.w * s, w1, true);
    uint2 o; o.x = (u32)w0; o.y = (u32)w1;
    ((uint2*)((char*)hb8 + (size_t)row * DIM + lane * 8))[0] = o;
}

// stage helper: immediate offset must be a constant-expression for
// __builtin_amdgcn_global_load_lds -> template parameter.
template <int K0OFF>
__device__ __forceinline__ void stage_tiles(
        const char* const* gA, const char* const* gB,
        char* ldsA, char* ldsB, int tid) {
#pragma unroll
    for (int s2 = 0; s2 < 4; ++s2) {
        int seg = tid + s2 * 256;
        __builtin_amdgcn_global_load_lds(
            (const __attribute__((address_space(1))) void*)gA[s2],
            (__attribute__((address_space(3))) void*)&ldsA[seg * 16],
            16, K0OFF, 0);
        __builtin_amdgcn_global_load_lds(
            (const __attribute__((address_space(1))) void*)gB[s2],
            (__attribute__((address_space(3))) void*)&ldsB[seg * 16],
            16, K0OFF, 0);
    }
}

__device__ __forceinline__ float agent_load(const float* p) {
    // coherent-point load: other XCDs' atomicAdd results, bypassing stale L1/L2
    return __hip_atomic_load(p, __ATOMIC_RELAXED, __HIP_MEMORY_SCOPE_AGENT);
}

// ------- kernel 2: persistent triangular fused tile GEMM (fp8) -------------
// R2-PROVEN inner core (stage -> sync -> compute -> sync per BK=128, VGPR 76,
// 54.7us measured). NEW: 1024 persistent blocks work-steal tiles via global
// counter (load-balance + full 4-blocks/CU residency vs R2's measured 2.2);
// last-64 blocks spin until all finish, then fold the loss 128 rows each
// (replaces R6's 46us single-block serial tail AND the 3rd kernel launch).
__global__ __launch_bounds__(256) void tile_kernel(
        const char* __restrict__ hb8, const int* __restrict__ labels,
        float* __restrict__ rowTotalR, float* __restrict__ rowPosR,
        u32* __restrict__ cnt, float* __restrict__ out) {
    __shared__ __align__(16) char ldsA[BM * 128];   // 16 KB
    __shared__ __align__(16) char ldsB[BN * 128];   // 16 KB
    __shared__ int labR[BM];
    __shared__ int labC[BN];
    __shared__ float cT[2][BN], cP[2][BN];
    __shared__ float rT[2][BM], rP[2][BM];
    __shared__ int sIdx;

    const int tid = threadIdx.x;
    const int w = tid >> 6;
    const int lane = tid & 63;
    const int wm = (w >> 1) * 64;
    const int wn = (w & 1) * 64;
    const int wr = w >> 1;
    const int wc = w & 1;
    const int quad = lane >> 4;
    const int l16 = lane & 15;

    for (;;) {
        if (tid == 0) sIdx = (int)atomicAdd(&cnt[0], 1u);
        __syncthreads();      // broadcast steal; also orders LDS reuse vs prev tile
        const int s = sIdx;
        if (s >= NTILES) break;
        const int p = s / 65;             // pair id [0,32)
        const int t = s - p * 65;         // tile within pair [0,65)
        int ti, tj;
        if (t <= p) { tj = p; ti = t; }
        else        { tj = 63 - p; ti = t - p - 1; }

        const int rowBase = ti * BM;
        const int colBase = tj * BN;
        const bool isDiag = (ti == tj);
        const int dd = colBase - rowBase;
        const int rep = (ti + tj) & (NREP - 1);

        if (tid < 128) labR[tid] = labels[rowBase + tid];
        else           labC[tid - 128] = labels[colBase + tid - 128];

        // staging bases (k0 advances via immediate offset)
        const char* gA[4]; const char* gB[4];
#pragma unroll
        for (int s2 = 0; s2 < 4; ++s2) {
            int seg = tid + s2 * 256;         // 0..1023
            int r = seg >> 3;                 // 0..127
            int sl = seg & 7;                 // LDS 16-B slot
            int g = sl ^ (r & 7);             // global chunk within 128-B row-slice
            gA[s2] = hb8 + (size_t)(rowBase + r) * DIM + g * 16;
            gB[s2] = hb8 + (size_t)(colBase + r) * DIM + g * 16;
        }

        f32x4 acc[4][4];
#pragma unroll
        for (int i = 0; i < 4; ++i)
#pragma unroll
            for (int jj = 0; jj < 4; ++jj)
                acc[i][jj] = (f32x4){0.f, 0.f, 0.f, 0.f};

#pragma unroll
        for (int k0 = 0; k0 < 4; ++k0) {      // BK=128 bytes, imm offset k0*128
            switch (k0) {
                case 0: stage_tiles<0>(gA, gB, ldsA, ldsB, tid); break;
                case 1: stage_tiles<128>(gA, gB, ldsA, ldsB, tid); break;
                case 2: stage_tiles<256>(gA, gB, ldsA, ldsB, tid); break;
                default: stage_tiles<384>(gA, gB, ldsA, ldsB, tid); break;
            }
            __syncthreads();                  // drain + barrier
#pragma unroll
            for (int kk = 0; kk < 4; ++kk) {  // four K=32 MFMA steps per BK=128
                long af[4], bfr[4];
#pragma unroll
                for (int im = 0; im < 4; ++im) {
                    int row = wm + im * 16 + l16;
                    int c4 = kk * 2 + (quad >> 1);
                    int sl = c4 ^ (row & 7);
                    af[im] = *(const long*)&ldsA[row * 128 + sl * 16 + (quad & 1) * 8];
                }
#pragma unroll
                for (int in = 0; in < 4; ++in) {
                    int col = wn + in * 16 + l16;
                    int c4 = kk * 2 + (quad >> 1);
                    int sl = c4 ^ (col & 7);
                    bfr[in] = *(const long*)&ldsB[col * 128 + sl * 16 + (quad & 1) * 8];
                }
#pragma unroll
                for (int im = 0; im < 4; ++im)
#pragma unroll
                    for (int in = 0; in < 4; ++in)
                        acc[im][in] = __builtin_amdgcn_mfma_f32_16x16x32_fp8_fp8(
                            af[im], bfr[in], acc[im][in], 0, 0, 0);
            }
            __syncthreads();                  // protect buffers before next stage
        }

        // ------------- epilogue (acc already = sim/T * log2e) -------------
        int lc[4];
#pragma unroll
        for (int in = 0; in < 4; ++in) lc[in] = labC[wn + in * 16 + l16];

        float colT[4] = {0.f, 0.f, 0.f, 0.f}, colP[4] = {0.f, 0.f, 0.f, 0.f};
#pragma unroll
        for (int im = 0; im < 4; ++im) {
            float rowT[4] = {0.f, 0.f, 0.f, 0.f}, rowP[4] = {0.f, 0.f, 0.f, 0.f};
#pragma unroll
            for (int reg = 0; reg < 4; ++reg) {
                int rloc = wm + im * 16 + quad * 4 + reg;
                int li = labR[rloc];
#pragma unroll
                for (int in = 0; in < 4; ++in) {
                    int cloc = wn + in * 16 + l16;
                    float e = __builtin_exp2f(acc[im][in][reg]);  // v_exp_f32
                    bool pos = (lc[in] == li) && (rloc - cloc != dd);
                    colT[in] += e; rowT[reg] += e;
                    if (pos) { colP[in] += e; rowP[reg] += e; }
                }
            }
            if (!isDiag) {
#pragma unroll
                for (int reg = 0; reg < 4; ++reg) {
                    float tt = rowT[reg], pp = rowP[reg];
                    tt += __shfl_xor(tt, 1); tt += __shfl_xor(tt, 2);
                    tt += __shfl_xor(tt, 4); tt += __shfl_xor(tt, 8);
                    pp += __shfl_xor(pp, 1); pp += __shfl_xor(pp, 2);
                    pp += __shfl_xor(pp, 4); pp += __shfl_xor(pp, 8);
                    if (l16 == 0) {
                        int rloc = wm + im * 16 + quad * 4 + reg;
                        rT[wc][rloc] = tt;
                        rP[wc][rloc] = pp;
                    }
                }
            }
        }
#pragma unroll
        for (int in = 0; in < 4; ++in) {
            float tt = colT[in], pp = colP[in];
            tt += __shfl_xor(tt, 16); tt += __shfl_xor(tt, 32);
            pp += __shfl_xor(pp, 16); pp += __shfl_xor(pp, 32);
            if (quad == 0) {
                int cloc = wn + in * 16 + l16;
                cT[wr][cloc] = tt;
                cP[wr][cloc] = pp;
            }
        }
        __syncthreads();
        float* rowTotal = rowTotalR + rep * N_ROWS;
        float* rowPos   = rowPosR   + rep * N_ROWS;
        if (tid < 128) {
            atomicAdd(&rowTotal[colBase + tid], cT[0][tid] + cT[1][tid]);
            if (!isDiag) atomicAdd(&rowTotal[rowBase + tid], rT[0][tid] + rT[1][tid]);
        } else {
            int t2 = tid - 128;
            atomicAdd(&rowPos[colBase + t2], cP[0][t2] + cP[1][t2]);
            if (!isDiag) atomicAdd(&rowPos[rowBase + t2], rP[0][t2] + rP[1][t2]);
        }
        // loop: next steal's __syncthreads orders all LDS rewrites
    }

    // -------- finish: last-64 incrementers fold the loss in parallel --------
    if (tid == 0) {
        __threadfence();                      // our atomics visible device-wide
        sIdx = (int)atomicAdd(&cnt[1], 1u);
    }
    __syncthreads();
    const int o = sIdx;
    if (o < GRID_P - FINB) return;            // early finishers exit
    // Spinners appear only when <=64 blocks remain unfinished -> no deadlock:
    // every other block exits right after incrementing, freeing its CU slot.
    if (tid == 0) {
        while (__hip_atomic_load(&cnt[1], __ATOMIC_ACQUIRE,
                                 __HIP_MEMORY_SCOPE_AGENT) < (u32)GRID_P)
            __builtin_amdgcn_s_sleep(8);
    }
    __syncthreads();
    const int slice = o - (GRID_P - FINB);    // [0,64): 128 rows each
    int* hist = labR;                          // reuse LDS
    float* red = &cT[0][0];                    // 256 floats
    if (tid < 128) hist[tid] = 0;
    __syncthreads();
    for (int i = tid; i < N_ROWS; i += 256)
        atomicAdd(&hist[labels[i] & 127], 1);
    __syncthreads();
    float sacc = 0.f;
    if (tid < 128) {
        int row = slice * 128 + tid;
        float T = 0.f, P = 0.f;
#pragma unroll
        for (int r = 0; r < NREP; ++r) {
            T += agent_load(&rowTotalR[r * N_ROWS + row]);
            P += agent_load(&rowPosR[r * N_ROWS + row]);
        }
        float cc = (float)(hist[labels[row] & 127] - 1);
        sacc = logf((P / (cc + 1e-9f)) / T);
    }
    red[tid] = sacc;
    __syncthreads();
    for (int st = 128; st; st >>= 1) {
        if (tid < st) red[tid] += red[tid + st];
        __syncthreads();
    }
    if (tid == 0) atomicAdd(out, -red[0] / (float)N_ROWS);
}

extern "C" void kernel_launch(void* const* d_in, const int* in_sizes, int n_in,
                              void* d_out, int out_size, void* d_ws, size_t ws_size,
                              hipStream_t stream) {
    const float* hidden = (const float*)d_in[0];
    const int* labels   = (const int*)d_in[1];
    float* out = (float*)d_out;

    char* ws = (char*)d_ws;
    char* hb8 = ws;                                          // 8192*512 = 4 MB
    float* rowTotalR = (float*)(ws + (size_t)N_ROWS * DIM);  // NREP*8192 f
    float* rowPosR   = rowTotalR + NREP * N_ROWS;            // NREP*8192 f
    u32* cnt         = (u32*)(rowPosR + NREP * N_ROWS);      // 2 u32

    norm_cast_kernel<<<N_ROWS / 4, 256, 0, stream>>>(hidden, (u32*)hb8, rowTotalR, out, cnt);
    tile_kernel<<<GRID_P, 256, 0, stream>>>(hb8, labels, rowTotalR, rowPosR, cnt, out);
}

// Round 8
// 146.904 us; speedup vs baseline: 1.1541x; 1.0796x over previous
//
#include <hip/hip_runtime.h>
#include <hip/hip_bf16.h>

typedef unsigned short u16;
typedef unsigned int u32;
typedef float f32x4 __attribute__((ext_vector_type(4)));

#define N_ROWS 8192
#define DIM 512
#define BM 256
#define BN 256
#define NREP 8             // accumulator replicas
#define NT_TILES 528       // 16 pairs * 33 tiles (32x32 triangular w/ diagonal)
// sqrt(log2(e)/0.07): folded into stored fp8 so MFMA emits sim/T*log2(e)
// directly and the epilogue uses raw v_exp_f32 (exp2) with no extra mul.
#define SCALE 4.5398160f

// ------- kernel 1: L2-normalize rows -> fp8 e4m3 (pre-scaled); zero accs ---
__global__ __launch_bounds__(256) void norm_cast_kernel(
        const float* __restrict__ x, u32* __restrict__ hb8,
        float* __restrict__ accR /* 2*NREP*N_ROWS floats */,
        float* __restrict__ out) {
    int gid = blockIdx.x * 256 + threadIdx.x;
    if (gid < 2 * NREP * N_ROWS) accR[gid] = 0.f;
    if (gid == 0) out[0] = 0.f;
    int row  = blockIdx.x * 4 + (threadIdx.x >> 6);
    int lane = threadIdx.x & 63;
    const float4* xr = (const float4*)(x + (size_t)row * DIM);
    float4 v0 = xr[lane * 2 + 0];
    float4 v1 = xr[lane * 2 + 1];
    float ss = v0.x * v0.x + v0.y * v0.y + v0.z * v0.z + v0.w * v0.w
             + v1.x * v1.x + v1.y * v1.y + v1.z * v1.z + v1.w * v1.w;
#pragma unroll
    for (int off = 32; off; off >>= 1) ss += __shfl_xor(ss, off);
    float s = SCALE / fmaxf(sqrtf(ss), 1e-12f);
    // pack 8 fp8 (OCP e4m3 on gfx950, RNE+sat in HW)
    int w0 = __builtin_amdgcn_cvt_pk_fp8_f32(v0.x * s, v0.y * s, 0, false);
    w0     = __builtin_amdgcn_cvt_pk_fp8_f32(v0.z * s, v0.w * s, w0, true);
    int w1 = __builtin_amdgcn_cvt_pk_fp8_f32(v1.x * s, v1.y * s, 0, false);
    w1     = __builtin_amdgcn_cvt_pk_fp8_f32(v1.z * s, v1.w * s, w1, true);
    uint2 o; o.x = (u32)w0; o.y = (u32)w1;
    ((uint2*)((char*)hb8 + (size_t)row * DIM + lane * 8))[0] = o;
}

// stage helper (512 threads): 4 A-chunks + 4 B-chunks per thread per BK=128.
// LDS dest linear in tid per instruction (wave-uniform base + lane*16).
template <int K0OFF>
__device__ __forceinline__ void stage_tiles(
        const char* const* gA, const char* const* gB,
        char* ldsA, char* ldsB, int tid) {
#pragma unroll
    for (int s2 = 0; s2 < 4; ++s2) {
        int seg = tid + s2 * 512;          // 0..2047
        __builtin_amdgcn_global_load_lds(
            (const __attribute__((address_space(1))) void*)gA[s2],
            (__attribute__((address_space(3))) void*)&ldsA[seg * 16],
            16, K0OFF, 0);
        __builtin_amdgcn_global_load_lds(
            (const __attribute__((address_space(1))) void*)gB[s2],
            (__attribute__((address_space(3))) void*)&ldsB[seg * 16],
            16, K0OFF, 0);
    }
}

// ------- kernel 2: triangular fused 256x256-tile GEMM (fp8) + exp2 + sums --
// R2-proven discipline (stage -> sync -> compute -> sync per BK=128, same
// XOR swizzle, same fragment formulas). NEW geometry only: BM=BN=256,
// 512 threads = 8 waves (2x4), wave tile 128x64, acc[8][4]. Tiles 2080->528,
// barriers/FLOP /4, staged bytes/FLOP /2 -> attacks R2's ~18us wait share.
// 3-kernel structure retained (fusion/persistence both measured worse R6/R7).
__global__ __launch_bounds__(512, 2) void tile_kernel(
        const char* __restrict__ hb8, const int* __restrict__ labels,
        float* __restrict__ rowTotalR, float* __restrict__ rowPosR) {
    __shared__ __align__(16) char ldsA[BM * 128];   // 32 KB
    __shared__ __align__(16) char ldsB[BN * 128];   // 32 KB
    __shared__ int labR[BM];
    __shared__ int labC[BN];
    __shared__ float cT[2][BN], cP[2][BN];          // per-wr column sums
    __shared__ float rT[4][BM], rP[4][BM];          // per-wc row sums

    const int b = blockIdx.x;          // 0..527
    const int p = b / 33;              // pair id [0,16)
    const int t = b - p * 33;          // tile within pair [0,33)
    int ti, tj;
    if (t <= p) { tj = p; ti = t; }
    else        { tj = 31 - p; ti = t - p - 1; }

    const int rowBase = ti * BM;
    const int colBase = tj * BN;
    const bool isDiag = (ti == tj);
    const int dd = colBase - rowBase;
    const int rep = (ti + tj) & (NREP - 1);
    const int tid = threadIdx.x;

    if (tid < 256) labR[tid] = labels[rowBase + tid];
    else           labC[tid - 256] = labels[colBase + tid - 256];

    const int w = tid >> 6;            // 0..7
    const int lane = tid & 63;
    const int wr = w >> 2;             // 0..1  (row half)
    const int wc = w & 3;              // 0..3  (col quarter)
    const int wm = wr * 128;
    const int wn = wc * 64;
    const int quad = lane >> 4;
    const int l16 = lane & 15;

    // staging bases (computed once; k0 advances via immediate offset)
    const char* gA[4]; const char* gB[4];
#pragma unroll
    for (int s2 = 0; s2 < 4; ++s2) {
        int seg = tid + s2 * 512;          // 0..2047
        int r = seg >> 3;                  // 0..255
        int sl = seg & 7;                  // LDS 16-B slot
        int g = sl ^ (r & 7);              // global chunk within 128-B row-slice
        gA[s2] = hb8 + (size_t)(rowBase + r) * DIM + g * 16;
        gB[s2] = hb8 + (size_t)(colBase + r) * DIM + g * 16;
    }

    f32x4 acc[8][4];
#pragma unroll
    for (int i = 0; i < 8; ++i)
#pragma unroll
        for (int jj = 0; jj < 4; ++jj)
            acc[i][jj] = (f32x4){0.f, 0.f, 0.f, 0.f};

#pragma unroll
    for (int k0 = 0; k0 < 4; ++k0) {      // BK=128 bytes, imm offset k0*128
        switch (k0) {
            case 0: stage_tiles<0>(gA, gB, ldsA, ldsB, tid); break;
            case 1: stage_tiles<128>(gA, gB, ldsA, ldsB, tid); break;
            case 2: stage_tiles<256>(gA, gB, ldsA, ldsB, tid); break;
            default: stage_tiles<384>(gA, gB, ldsA, ldsB, tid); break;
        }
        __syncthreads();                  // drain + barrier
#pragma unroll
        for (int kk = 0; kk < 4; ++kk) {  // four K=32 MFMA steps per BK=128
            long af[8], bfr[4];
#pragma unroll
            for (int in = 0; in < 4; ++in) {
                int col = wn + in * 16 + l16;
                int c4 = kk * 2 + (quad >> 1);
                int sl = c4 ^ (col & 7);
                bfr[in] = *(const long*)&ldsB[col * 128 + sl * 16 + (quad & 1) * 8];
            }
#pragma unroll
            for (int im = 0; im < 8; ++im) {
                int row = wm + im * 16 + l16;
                int c4 = kk * 2 + (quad >> 1);
                int sl = c4 ^ (row & 7);
                af[im] = *(const long*)&ldsA[row * 128 + sl * 16 + (quad & 1) * 8];
            }
#pragma unroll
            for (int im = 0; im < 8; ++im)
#pragma unroll
                for (int in = 0; in < 4; ++in)
                    acc[im][in] = __builtin_amdgcn_mfma_f32_16x16x32_fp8_fp8(
                        af[im], bfr[in], acc[im][in], 0, 0, 0);
        }
        __syncthreads();                  // protect buffers before next stage
    }

    // ---------------- epilogue (acc already = sim/T * log2e) ----------------
    int lc[4];
#pragma unroll
    for (int in = 0; in < 4; ++in) lc[in] = labC[wn + in * 16 + l16];

    float colT[4] = {0.f, 0.f, 0.f, 0.f}, colP[4] = {0.f, 0.f, 0.f, 0.f};
#pragma unroll
    for (int im = 0; im < 8; ++im) {
        float rowT[4] = {0.f, 0.f, 0.f, 0.f}, rowP[4] = {0.f, 0.f, 0.f, 0.f};
#pragma unroll
        for (int reg = 0; reg < 4; ++reg) {
            int rloc = wm + im * 16 + quad * 4 + reg;
            int li = labR[rloc];
#pragma unroll
            for (int in = 0; in < 4; ++in) {
                int cloc = wn + in * 16 + l16;
                float e = __builtin_exp2f(acc[im][in][reg]);  // v_exp_f32
                bool pos = (lc[in] == li) && (rloc - cloc != dd);
                colT[in] += e; rowT[reg] += e;
                if (pos) { colP[in] += e; rowP[reg] += e; }
            }
        }
        if (!isDiag) {
#pragma unroll
            for (int reg = 0; reg < 4; ++reg) {
                float tt = rowT[reg], pp = rowP[reg];
                tt += __shfl_xor(tt, 1); tt += __shfl_xor(tt, 2);
                tt += __shfl_xor(tt, 4); tt += __shfl_xor(tt, 8);
                pp += __shfl_xor(pp, 1); pp += __shfl_xor(pp, 2);
                pp += __shfl_xor(pp, 4); pp += __shfl_xor(pp, 8);
                if (l16 == 0) {
                    int rloc = wm + im * 16 + quad * 4 + reg;
                    rT[wc][rloc] = tt;
                    rP[wc][rloc] = pp;
                }
            }
        }
    }
#pragma unroll
    for (int in = 0; in < 4; ++in) {
        float tt = colT[in], pp = colP[in];
        tt += __shfl_xor(tt, 16); tt += __shfl_xor(tt, 32);
        pp += __shfl_xor(pp, 16); pp += __shfl_xor(pp, 32);
        if (quad == 0) {
            int cloc = wn + in * 16 + l16;
            cT[wr][cloc] = tt;
            cP[wr][cloc] = pp;
        }
    }
    __syncthreads();
    float* rowTotal = rowTotalR + rep * N_ROWS;
    float* rowPos   = rowPosR   + rep * N_ROWS;
    if (tid < 256) {
        // column contributions (always, incl. diagonal tiles)
        atomicAdd(&rowTotal[colBase + tid], cT[0][tid] + cT[1][tid]);
        atomicAdd(&rowPos[colBase + tid],   cP[0][tid] + cP[1][tid]);
    } else if (!isDiag) {
        int r2 = tid - 256;
        atomicAdd(&rowTotal[rowBase + r2],
                  rT[0][r2] + rT[1][r2] + rT[2][r2] + rT[3][r2]);
        atomicAdd(&rowPos[rowBase + r2],
                  rP[0][r2] + rP[1][r2] + rP[2][r2] + rP[3][r2]);
    }
}

// ------- kernel 3: fold replicas + histogram + loss (64 blocks) ------------
__global__ __launch_bounds__(256) void reduce_loss_kernel(
        const int* __restrict__ labels, const float* __restrict__ rowTotalR,
        const float* __restrict__ rowPosR, float* __restrict__ out) {
    __shared__ int hist[128];
    __shared__ float red[256];
    int tid = threadIdx.x;
    if (tid < 128) hist[tid] = 0;
    __syncthreads();
    for (int i = tid; i < N_ROWS; i += 256)
        atomicAdd(&hist[labels[i] & 127], 1);
    __syncthreads();
    float sacc = 0.f;
    if (tid < 128) {
        int row = blockIdx.x * 128 + tid;
        float T = 0.f, P = 0.f;
#pragma unroll
        for (int r = 0; r < NREP; ++r) {
            T += rowTotalR[r * N_ROWS + row];
            P += rowPosR[r * N_ROWS + row];
        }
        float cc = (float)(hist[labels[row] & 127] - 1);
        sacc = logf((P / (cc + 1e-9f)) / T);
    }
    red[tid] = sacc;
    __syncthreads();
    for (int st = 128; st; st >>= 1) {
        if (tid < st) red[tid] += red[tid + st];
        __syncthreads();
    }
    if (tid == 0) atomicAdd(out, -red[0] / (float)N_ROWS);
}

extern "C" void kernel_launch(void* const* d_in, const int* in_sizes, int n_in,
                              void* d_out, int out_size, void* d_ws, size_t ws_size,
                              hipStream_t stream) {
    const float* hidden = (const float*)d_in[0];
    const int* labels   = (const int*)d_in[1];
    float* out = (float*)d_out;

    char* ws = (char*)d_ws;
    char* hb8 = ws;                                          // 8192*512 = 4 MB
    float* rowTotalR = (float*)(ws + (size_t)N_ROWS * DIM);  // NREP*8192 f
    float* rowPosR   = rowTotalR + NREP * N_ROWS;            // NREP*8192 f

    norm_cast_kernel<<<N_ROWS / 4, 256, 0, stream>>>(hidden, (u32*)hb8, rowTotalR, out);
    tile_kernel<<<NT_TILES, 512, 0, stream>>>(hb8, labels, rowTotalR, rowPosR);
    reduce_loss_kernel<<<64, 256, 0, stream>>>(labels, rowTotalR, rowPosR, out);
}

// Round 9
// 118.803 us; speedup vs baseline: 1.4271x; 1.2365x over previous
//
#include <hip/hip_runtime.h>
#include <hip/hip_bf16.h>

typedef unsigned short u16;
typedef unsigned int u32;
typedef float f32x4 __attribute__((ext_vector_type(4)));

#define N_ROWS 8192
#define DIM 512
#define BM 128
#define BN 128
#define NREP 8             // accumulator replicas
// sqrt(log2(e)/0.07): folded into stored fp8 so MFMA emits sim/T*log2(e)
// directly and the epilogue uses raw v_exp_f32 (exp2) with no extra mul.
#define SCALE 4.5398160f

// ------- kernel 1: L2-normalize rows -> fp8 e4m3 (pre-scaled); zero accs ---
__global__ __launch_bounds__(256) void norm_cast_kernel(
        const float* __restrict__ x, u32* __restrict__ hb8,
        float* __restrict__ accR /* 2*NREP*N_ROWS floats */,
        float* __restrict__ out) {
    int gid = blockIdx.x * 256 + threadIdx.x;
    if (gid < 2 * NREP * N_ROWS) accR[gid] = 0.f;
    if (gid == 0) out[0] = 0.f;
    int row  = blockIdx.x * 4 + (threadIdx.x >> 6);
    int lane = threadIdx.x & 63;
    const float4* xr = (const float4*)(x + (size_t)row * DIM);
    float4 v0 = xr[lane * 2 + 0];
    float4 v1 = xr[lane * 2 + 1];
    float ss = v0.x * v0.x + v0.y * v0.y + v0.z * v0.z + v0.w * v0.w
             + v1.x * v1.x + v1.y * v1.y + v1.z * v1.z + v1.w * v1.w;
#pragma unroll
    for (int off = 32; off; off >>= 1) ss += __shfl_xor(ss, off);
    float s = SCALE / fmaxf(sqrtf(ss), 1e-12f);
    // pack 8 fp8 (OCP e4m3 on gfx950, RNE+sat in HW)
    int w0 = __builtin_amdgcn_cvt_pk_fp8_f32(v0.x * s, v0.y * s, 0, false);
    w0     = __builtin_amdgcn_cvt_pk_fp8_f32(v0.z * s, v0.w * s, w0, true);
    int w1 = __builtin_amdgcn_cvt_pk_fp8_f32(v1.x * s, v1.y * s, 0, false);
    w1     = __builtin_amdgcn_cvt_pk_fp8_f32(v1.z * s, v1.w * s, w1, true);
    uint2 o; o.x = (u32)w0; o.y = (u32)w1;
    ((uint2*)((char*)hb8 + (size_t)row * DIM + lane * 8))[0] = o;
}

// stage helper: immediate offset must be a constant-expression for
// __builtin_amdgcn_global_load_lds -> template parameter.
template <int K0OFF>
__device__ __forceinline__ void stage_tiles(
        const char* const* gA, const char* const* gB,
        char* ldsA, char* ldsB, int tid) {
#pragma unroll
    for (int s2 = 0; s2 < 4; ++s2) {
        int seg = tid + s2 * 256;
        __builtin_amdgcn_global_load_lds(
            (const __attribute__((address_space(1))) void*)gA[s2],
            (__attribute__((address_space(3))) void*)&ldsA[seg * 16],
            16, K0OFF, 0);
        __builtin_amdgcn_global_load_lds(
            (const __attribute__((address_space(1))) void*)gB[s2],
            (__attribute__((address_space(3))) void*)&ldsB[seg * 16],
            16, K0OFF, 0);
    }
}

// ------- kernel 2: triangular fused tile GEMM (fp8) + exp2 + sums ----------
// R2-MEASURED core (54.7us tile, passed): stage -> sync -> compute -> sync.
// Single change this round: __launch_bounds__(256, 4) -> VGPR cap 128/wave
// (64 arch + 64 acc) -> 4 resident blocks/CU (was ~3 at 140 VGPR). Mechanism
// (m114, measured R2 vs R8): stage-drain waits are hidden ONLY by co-resident
// blocks; R8's 1-block/CU 256^2 tile exposed them (80.5us, same busy times).
__global__ __launch_bounds__(256, 4) void tile_kernel(
        const char* __restrict__ hb8, const int* __restrict__ labels,
        float* __restrict__ rowTotalR, float* __restrict__ rowPosR) {
    __shared__ __align__(16) char ldsA[BM * 128];   // 16 KB
    __shared__ __align__(16) char ldsB[BN * 128];   // 16 KB
    __shared__ int labR[BM];
    __shared__ int labC[BN];
    __shared__ float cT[2][BN], cP[2][BN];
    __shared__ float rT[2][BM], rP[2][BM];

    const int b = blockIdx.x;
    const int c = b & 255;          // CU slot (round-robin)
    const int m = b >> 8;           // step 0..8
    const int y = c >> 3;
    const int p = 4 * (c & 7) + (y & 3);    // pair id [0,32)
    const int j = y >> 2;                   // CU within pair [0,8)
    const int t = j + 8 * m;                // tile index within pair
    if (t >= 65) return;
    int ti, tj;
    if (t <= p) { tj = p; ti = t; }
    else        { tj = 63 - p; ti = t - p - 1; }

    const int rowBase = ti * BM;
    const int colBase = tj * BN;
    const bool isDiag = (ti == tj);
    const int dd = colBase - rowBase;
    const int rep = (ti + tj) & (NREP - 1);
    const int tid = threadIdx.x;

    if (tid < 128) labR[tid] = labels[rowBase + tid];
    else           labC[tid - 128] = labels[colBase + tid - 128];

    const int w = tid >> 6;
    const int lane = tid & 63;
    const int wm = (w >> 1) * 64;
    const int wn = (w & 1) * 64;
    const int wr = w >> 1;
    const int wc = w & 1;
    const int quad = lane >> 4;
    const int l16 = lane & 15;

    // staging bases (computed once; k0 advances via immediate offset)
    const char* gA[4]; const char* gB[4];
#pragma unroll
    for (int s2 = 0; s2 < 4; ++s2) {
        int seg = tid + s2 * 256;         // 0..1023
        int r = seg >> 3;                 // 0..127
        int sl = seg & 7;                 // LDS 16-B slot
        int g = sl ^ (r & 7);             // global 16-B chunk within 128-B row-slice
        gA[s2] = hb8 + (size_t)(rowBase + r) * DIM + g * 16;
        gB[s2] = hb8 + (size_t)(colBase + r) * DIM + g * 16;
    }

    f32x4 acc[4][4];
#pragma unroll
    for (int i = 0; i < 4; ++i)
#pragma unroll
        for (int jj = 0; jj < 4; ++jj)
            acc[i][jj] = (f32x4){0.f, 0.f, 0.f, 0.f};

#pragma unroll
    for (int k0 = 0; k0 < 4; ++k0) {      // BK=128 bytes, imm offset k0*128
        switch (k0) {
            case 0: stage_tiles<0>(gA, gB, ldsA, ldsB, tid); break;
            case 1: stage_tiles<128>(gA, gB, ldsA, ldsB, tid); break;
            case 2: stage_tiles<256>(gA, gB, ldsA, ldsB, tid); break;
            default: stage_tiles<384>(gA, gB, ldsA, ldsB, tid); break;
        }
        __syncthreads();                  // drain + barrier
#pragma unroll
        for (int kk = 0; kk < 4; ++kk) {  // four K=32 MFMA steps per BK=128
            long af[4], bfr[4];
#pragma unroll
            for (int im = 0; im < 4; ++im) {
                int row = wm + im * 16 + l16;
                int c4 = kk * 2 + (quad >> 1);
                int sl = c4 ^ (row & 7);
                af[im] = *(const long*)&ldsA[row * 128 + sl * 16 + (quad & 1) * 8];
            }
#pragma unroll
            for (int in = 0; in < 4; ++in) {
                int col = wn + in * 16 + l16;
                int c4 = kk * 2 + (quad >> 1);
                int sl = c4 ^ (col & 7);
                bfr[in] = *(const long*)&ldsB[col * 128 + sl * 16 + (quad & 1) * 8];
            }
#pragma unroll
            for (int im = 0; im < 4; ++im)
#pragma unroll
                for (int in = 0; in < 4; ++in)
                    acc[im][in] = __builtin_amdgcn_mfma_f32_16x16x32_fp8_fp8(
                        af[im], bfr[in], acc[im][in], 0, 0, 0);
        }
        __syncthreads();                  // protect buffers before next stage
    }

    // ---------------- epilogue (acc already = sim/T * log2e) ----------------
    int lc[4];
#pragma unroll
    for (int in = 0; in < 4; ++in) lc[in] = labC[wn + in * 16 + l16];

    float colT[4] = {0.f, 0.f, 0.f, 0.f}, colP[4] = {0.f, 0.f, 0.f, 0.f};
#pragma unroll
    for (int im = 0; im < 4; ++im) {
        float rowT[4] = {0.f, 0.f, 0.f, 0.f}, rowP[4] = {0.f, 0.f, 0.f, 0.f};
#pragma unroll
        for (int reg = 0; reg < 4; ++reg) {
            int rloc = wm + im * 16 + quad * 4 + reg;
            int li = labR[rloc];
#pragma unroll
            for (int in = 0; in < 4; ++in) {
                int cloc = wn + in * 16 + l16;
                float e = __builtin_exp2f(acc[im][in][reg]);  // v_exp_f32, no mul
                bool pos = (lc[in] == li) && (rloc - cloc != dd);
                colT[in] += e; rowT[reg] += e;
                if (pos) { colP[in] += e; rowP[reg] += e; }
            }
        }
        if (!isDiag) {
#pragma unroll
            for (int reg = 0; reg < 4; ++reg) {
                float tt = rowT[reg], pp = rowP[reg];
                tt += __shfl_xor(tt, 1); tt += __shfl_xor(tt, 2);
                tt += __shfl_xor(tt, 4); tt += __shfl_xor(tt, 8);
                pp += __shfl_xor(pp, 1); pp += __shfl_xor(pp, 2);
                pp += __shfl_xor(pp, 4); pp += __shfl_xor(pp, 8);
                if (l16 == 0) {
                    int rloc = wm + im * 16 + quad * 4 + reg;
                    rT[wc][rloc] = tt;
                    rP[wc][rloc] = pp;
                }
            }
        }
    }
#pragma unroll
    for (int in = 0; in < 4; ++in) {
        float tt = colT[in], pp = colP[in];
        tt += __shfl_xor(tt, 16); tt += __shfl_xor(tt, 32);
        pp += __shfl_xor(pp, 16); pp += __shfl_xor(pp, 32);
        if (quad == 0) {
            int cloc = wn + in * 16 + l16;
            cT[wr][cloc] = tt;
            cP[wr][cloc] = pp;
        }
    }
    __syncthreads();
    float* rowTotal = rowTotalR + rep * N_ROWS;
    float* rowPos   = rowPosR   + rep * N_ROWS;
    if (tid < 128) {
        atomicAdd(&rowTotal[colBase + tid], cT[0][tid] + cT[1][tid]);
        if (!isDiag) atomicAdd(&rowTotal[rowBase + tid], rT[0][tid] + rT[1][tid]);
    } else {
        int t2 = tid - 128;
        atomicAdd(&rowPos[colBase + t2], cP[0][t2] + cP[1][t2]);
        if (!isDiag) atomicAdd(&rowPos[rowBase + t2], rP[0][t2] + rP[1][t2]);
    }
}

// ------- kernel 3: fold replicas + histogram + loss (64 blocks) ------------
__global__ __launch_bounds__(256) void reduce_loss_kernel(
        const int* __restrict__ labels, const float* __restrict__ rowTotalR,
        const float* __restrict__ rowPosR, float* __restrict__ out) {
    __shared__ int hist[128];
    __shared__ float red[256];
    int tid = threadIdx.x;
    if (tid < 128) hist[tid] = 0;
    __syncthreads();
    for (int i = tid; i < N_ROWS; i += 256)
        atomicAdd(&hist[labels[i] & 127], 1);
    __syncthreads();
    float sacc = 0.f;
    if (tid < 128) {
        int row = blockIdx.x * 128 + tid;
        float T = 0.f, P = 0.f;
#pragma unroll
        for (int r = 0; r < NREP; ++r) {
            T += rowTotalR[r * N_ROWS + row];
            P += rowPosR[r * N_ROWS + row];
        }
        float cc = (float)(hist[labels[row] & 127] - 1);
        sacc = logf((P / (cc + 1e-9f)) / T);
    }
    red[tid] = sacc;
    __syncthreads();
    for (int st = 128; st; st >>= 1) {
        if (tid < st) red[tid] += red[tid + st];
        __syncthreads();
    }
    if (tid == 0) atomicAdd(out, -red[0] / (float)N_ROWS);
}

extern "C" void kernel_launch(void* const* d_in, const int* in_sizes, int n_in,
                              void* d_out, int out_size, void* d_ws, size_t ws_size,
                              hipStream_t stream) {
    const float* hidden = (const float*)d_in[0];
    const int* labels   = (const int*)d_in[1];
    float* out = (float*)d_out;

    char* ws = (char*)d_ws;
    char* hb8 = ws;                                          // 8192*512 = 4 MB
    float* rowTotalR = (float*)(ws + (size_t)N_ROWS * DIM);  // NREP*8192 f
    float* rowPosR   = rowTotalR + NREP * N_ROWS;            // NREP*8192 f

    norm_cast_kernel<<<N_ROWS / 4, 256, 0, stream>>>(hidden, (u32*)hb8, rowTotalR, out);
    tile_kernel<<<9 * 256, 256, 0, stream>>>(hb8, labels, rowTotalR, rowPosR);
    reduce_loss_kernel<<<64, 256, 0, stream>>>(labels, rowTotalR, rowPosR, out);
}